// Round 10
// baseline (82.921 us; speedup 1.0000x reference)
//
#include <hip/hip_runtime.h>
#include <cmath>

// Problem constants (from reference)
constexpr int N_GAUSS = 16;
constexpr int N_GRAPHS = 64;
constexpr int K_GRID = 4096;

// Table parameters
constexpr int NSEG = 512;             // segments over r in [0, RMAX]
constexpr int TSTRIDE = 528;          // floats per atom row in LDS (513 used + pad)
constexpr float RMAX = 12.0f;         // r2 <= 144; P(r>12) ~ 1e-15 for these inputs

// Decomposition: one dispatch; each block builds its 12-atom LDS table, then evals.
constexpr int KCHUNK = 256;           // threads per block
constexpr int KPER = 8;               // k-points per thread (independent chains)
constexpr int KSPAN = KCHUNK * KPER;  // 2048
constexpr int CHUNKS = K_GRID / KSPAN;// 2  (table redundancy = 2x)
constexpr int APB = 12;               // atoms per block (3072 % 12 == 0)

struct GaussParams {
    float ns2[N_GAUSS]; // -log2(e)/sigma^2
    float b[N_GAUSS];   // log2(sigma_r)
};

__device__ __forceinline__ float fast_exp2(float x) {
    return __builtin_amdgcn_exp2f(x);
}

// ---- Kernel 0: zero the output (atomics accumulate into it) ----
__global__ __launch_bounds__(256) void zero_out_kernel(float4* __restrict__ out4) {
    out4[blockIdx.x * 256 + threadIdx.x] = make_float4(0.f, 0.f, 0.f, 0.f);
}

// ---- Kernel 1: fused build(LDS) + gather/interp eval ----
__global__ __launch_bounds__(KCHUNK) void GaussianOrbital_kernel(
    const float* __restrict__ coeff,       // (N_ATOMS, 16)
    const float* __restrict__ atom_coord,  // (N_ATOMS, 3)
    const float* __restrict__ grid,        // (N_GRAPHS, K_GRID, 3)
    const int* __restrict__ batch,         // (N_ATOMS,) sorted graph ids
    float* __restrict__ out,               // (N_GRAPHS, K_GRID), pre-zeroed
    GaussParams p, int n_atoms)
{
    __shared__ float lds[APB * TSTRIDE];   // 25,344 B

    const int chunk = blockIdx.x;          // 0..CHUNKS-1
    const int ablk  = blockIdx.y;          // 0..(n_atoms/APB)-1
    const int t = (int)threadIdx.x;

    const int lo = ablk * APB;
    int hi = lo + APB; if (hi > n_atoms) hi = n_atoms;

    // ---- Build phase: per-atom radial tables straight into LDS ----
    // Atom loop is uniform -> coeff row goes through the scalar path.
    for (int a = lo; a < hi; ++a) {
        const float* __restrict__ cf = coeff + a * N_GAUSS;  // wave-uniform
        float* __restrict__ T = lds + (a - lo) * TSTRIDE;
        for (int e = t; e <= NSEG; e += KCHUNK) {
            const float r = (float)e * (RMAX / (float)NSEG);
            const float r2 = r * r;
            float a0 = 0.f, a1 = 0.f, a2 = 0.f, a3 = 0.f;
            #pragma unroll
            for (int g = 0; g < N_GAUSS; g += 4) {
                a0 = fmaf(cf[g + 0], fast_exp2(fmaf(r2, p.ns2[g + 0], p.b[g + 0])), a0);
                a1 = fmaf(cf[g + 1], fast_exp2(fmaf(r2, p.ns2[g + 1], p.b[g + 1])), a1);
                a2 = fmaf(cf[g + 2], fast_exp2(fmaf(r2, p.ns2[g + 2], p.b[g + 2])), a2);
                a3 = fmaf(cf[g + 3], fast_exp2(fmaf(r2, p.ns2[g + 3], p.b[g + 3])), a3);
            }
            T[e] = (a0 + a1) + (a2 + a3);
        }
    }
    __syncthreads();

    // ---- Eval phase ----
    int cur_g = __builtin_amdgcn_readfirstlane(batch[lo]);

    float kx[KPER], ky[KPER], kz[KPER], acc[KPER];
    auto load_grid = [&](int g) {
        #pragma unroll
        for (int j = 0; j < KPER; ++j) {
            const int k = chunk * KSPAN + j * KCHUNK + t;
            const int b = (g * K_GRID + k) * 3;
            kx[j] = grid[b + 0]; ky[j] = grid[b + 1]; kz[j] = grid[b + 2];
        }
    };
    auto flush = [&](int g) {
        #pragma unroll
        for (int j = 0; j < KPER; ++j) {
            const int k = chunk * KSPAN + j * KCHUNK + t;
            atomicAdd(&out[g * K_GRID + k], acc[j]);
            acc[j] = 0.f;
        }
    };
    load_grid(cur_g);
    #pragma unroll
    for (int j = 0; j < KPER; ++j) acc[j] = 0.f;

    for (int a = lo; a < hi; ++a) {
        const int g = __builtin_amdgcn_readfirstlane(batch[a]);
        if (g != cur_g) {            // wave-uniform branch
            flush(cur_g);
            cur_g = g;
            load_grid(cur_g);
        }

        // wave-uniform scalar loads (constant-cache path)
        const float ax = atom_coord[a * 3 + 0];
        const float ay = atom_coord[a * 3 + 1];
        const float az = atom_coord[a * 3 + 2];
        const float* __restrict__ T = lds + (a - lo) * TSTRIDE;

        // Batched: 8 r2 -> 8 sqrt -> 8 gathers -> 8 fma (independent chains)
        float fr[KPER]; int ii[KPER];
        #pragma unroll
        for (int j = 0; j < KPER; ++j) {
            const float dx = kx[j] - ax, dy = ky[j] - ay, dz = kz[j] - az;
            const float r2 = fmaf(dx, dx, fmaf(dy, dy, dz * dz));
            float tt = __builtin_amdgcn_sqrtf(r2) * ((float)NSEG / RMAX);
            tt = fminf(tt, (float)(NSEG - 1));
            const int i = (int)tt;            // tt >= 0: trunc == floor
            fr[j] = tt - (float)i;
            ii[j] = i;
        }
        float f0[KPER], f1[KPER];
        #pragma unroll
        for (int j = 0; j < KPER; ++j) { f0[j] = T[ii[j]]; f1[j] = T[ii[j] + 1]; }
        #pragma unroll
        for (int j = 0; j < KPER; ++j) acc[j] = acc[j] + fmaf(fr[j], f1[j] - f0[j], f0[j]);
    }

    flush(cur_g);
}

extern "C" void kernel_launch(void* const* d_in, const int* in_sizes, int n_in,
                              void* d_out, int out_size, void* d_ws, size_t ws_size,
                              hipStream_t stream)
{
    const float* coeff      = (const float*)d_in[0];
    const float* atom_coord = (const float*)d_in[1];
    const float* grid       = (const float*)d_in[2];
    const int*   batch      = (const int*)d_in[3];
    float* out = (float*)d_out;
    const int n_atoms = in_sizes[0] / N_GAUSS;

    GaussParams p;
    const double sqrt2pi = 2.50662827463100050242;
    for (int g = 0; g < N_GAUSS; ++g) {
        const double sigma = 0.5 + (5.0 - 0.5) * (double)g / (double)(N_GAUSS - 1);
        p.ns2[g] = (float)(-1.44269504088896340736 / (sigma * sigma));
        const double sr = 1.0 / (sigma * sqrt2pi * sigma * sqrt2pi * sigma * sqrt2pi);
        p.b[g] = (float)(std::log2(sr));
    }

    // 0) zero the output (1 MB; atomics accumulate into it)
    {
        const int nvec4 = (N_GRAPHS * K_GRID) / 4;        // 65536 float4
        hipLaunchKernelGGL(zero_out_kernel, dim3(nvec4 / 256), dim3(256), 0, stream,
                           (float4*)out);
    }
    // 1) fused build + eval (single fat dispatch, no d_ws use)
    {
        const int n_ablk = (n_atoms + APB - 1) / APB;     // 256
        dim3 gDim(CHUNKS, n_ablk);
        hipLaunchKernelGGL(GaussianOrbital_kernel, gDim, dim3(KCHUNK), 0, stream,
                           coeff, atom_coord, grid, batch, out, p, n_atoms);
    }
}

// Round 11
// 82.813 us; speedup vs baseline: 1.0013x; 1.0013x over previous
//
#include <hip/hip_runtime.h>
#include <hip/hip_fp16.h>
#include <cmath>

// Problem constants (from reference)
constexpr int N_GAUSS = 16;
constexpr int N_GRAPHS = 64;
constexpr int K_GRID = 4096;

// Table: per-atom radial lookup, entry e (e=0..511) = half2 {f(r_e), f(r_{e+1})-f(r_e)}
constexpr int NSEG = 512;
constexpr int TSTRIDEP = 520;         // uint (=half2) per atom row: 512 used + pad (uint4-able)
constexpr float RMAX = 12.0f;         // r2 <= 144; P(r>12) ~ 1e-15 for these inputs

// Main kernel decomposition (R6/R9 best config)
constexpr int KCHUNK = 256;           // threads per block
constexpr int KPER = 4;               // k-points per thread (independent chains for ILP)
constexpr int KSPAN = KCHUNK * KPER;  // 1024
constexpr int CHUNKS = K_GRID / KSPAN;// 4
constexpr int APB = 12;               // atoms per block (3072 % 12 == 0)

struct GaussParams {
    float ns2[N_GAUSS]; // -log2(e)/sigma^2
    float b[N_GAUSS];   // log2(sigma_r)
};

__device__ __forceinline__ float fast_exp2(float x) {
    return __builtin_amdgcn_exp2f(x);
}

// ---- Kernel 1: build packed half2 radial tables + fused zeroing of out ----
// grid = (2, n_atoms), block = 256. Block bx covers entries n = bx*256+t (n<512);
// neighbor f values via LDS bounce (thread 255 computes one extra node).
__global__ __launch_bounds__(256) void build_table_kernel(
    const float* __restrict__ coeff,   // (N_ATOMS, 16)
    unsigned int* __restrict__ table,  // (N_ATOMS, TSTRIDEP) packed half2
    float* __restrict__ out,           // (N_GRAPHS*K_GRID) -- zeroed here
    GaussParams p)
{
    __shared__ float fv[257];
    const int a = blockIdx.y;
    const int t = (int)threadIdx.x;
    const int n = blockIdx.x * 256 + t;

    // Fused zero-init of out: blocks (bx==0, a<64) cover 64*256 float4 = 1 MB
    if (blockIdx.x == 0 && a < (N_GRAPHS * K_GRID) / (256 * 4)) {
        ((float4*)out)[a * 256 + t] = make_float4(0.f, 0.f, 0.f, 0.f);
    }

    const float* __restrict__ cf = coeff + a * N_GAUSS; // wave-uniform -> s_load

    auto eval = [&](int idx) -> float {
        const float r = (float)idx * (RMAX / (float)NSEG);
        const float r2 = r * r;
        float a0 = 0.f, a1 = 0.f, a2 = 0.f, a3 = 0.f;
        #pragma unroll
        for (int g = 0; g < N_GAUSS; g += 4) {
            a0 = fmaf(cf[g + 0], fast_exp2(fmaf(r2, p.ns2[g + 0], p.b[g + 0])), a0);
            a1 = fmaf(cf[g + 1], fast_exp2(fmaf(r2, p.ns2[g + 1], p.b[g + 1])), a1);
            a2 = fmaf(cf[g + 2], fast_exp2(fmaf(r2, p.ns2[g + 2], p.b[g + 2])), a2);
            a3 = fmaf(cf[g + 3], fast_exp2(fmaf(r2, p.ns2[g + 3], p.b[g + 3])), a3);
        }
        return (a0 + a1) + (a2 + a3);
    };

    fv[t] = eval(n);
    if (t == 255) fv[256] = eval(n + 1);
    __syncthreads();
    const float f0 = fv[t];
    const float f1 = fv[t + 1];
    const __half2 h2 = __halves2half2(__float2half(f0), __float2half(f1 - f0));
    unsigned int u;
    __builtin_memcpy(&u, &h2, 4);
    table[(size_t)a * TSTRIDEP + n] = u;
}

// ---- Kernel 2: gather + interp, 4 k-points per thread, half2 gathers ----
__global__ __launch_bounds__(KCHUNK) void GaussianOrbital_kernel(
    const unsigned int* __restrict__ table,// (N_ATOMS, TSTRIDEP)
    const float* __restrict__ atom_coord,  // (N_ATOMS, 3)
    const float* __restrict__ grid,        // (N_GRAPHS, K_GRID, 3)
    const int* __restrict__ batch,         // (N_ATOMS,) sorted graph ids
    float* __restrict__ out,               // (N_GRAPHS, K_GRID), pre-zeroed by build
    int n_atoms)
{
    __shared__ unsigned int lds[APB * TSTRIDEP];   // 12*520*4 = 24,960 B

    const int chunk = blockIdx.x;          // 0..CHUNKS-1
    const int ablk  = blockIdx.y;          // 0..(n_atoms/APB)-1
    const int t = (int)threadIdx.x;

    const int lo = ablk * APB;
    int hi = lo + APB; if (hi > n_atoms) hi = n_atoms;

    // Stage this block's packed atom tables into LDS (contiguous, vectorized)
    {
        const uint4* __restrict__ src = (const uint4*)(table + (size_t)lo * TSTRIDEP);
        uint4* dst = (uint4*)lds;
        const int nvec = (hi - lo) * TSTRIDEP / 4;   // 1560
        #pragma unroll 2
        for (int i = t; i < nvec; i += KCHUNK) dst[i] = src[i];
    }
    __syncthreads();

    int cur_g = __builtin_amdgcn_readfirstlane(batch[lo]);

    float kx[KPER], ky[KPER], kz[KPER], acc[KPER];
    auto load_grid = [&](int g) {
        #pragma unroll
        for (int j = 0; j < KPER; ++j) {
            const int k = chunk * KSPAN + j * KCHUNK + t;
            const int b = (g * K_GRID + k) * 3;
            kx[j] = grid[b + 0]; ky[j] = grid[b + 1]; kz[j] = grid[b + 2];
        }
    };
    auto flush = [&](int g) {
        #pragma unroll
        for (int j = 0; j < KPER; ++j) {
            const int k = chunk * KSPAN + j * KCHUNK + t;
            atomicAdd(&out[g * K_GRID + k], acc[j]);
            acc[j] = 0.f;
        }
    };
    load_grid(cur_g);
    #pragma unroll
    for (int j = 0; j < KPER; ++j) acc[j] = 0.f;

    for (int a = lo; a < hi; ++a) {
        const int g = __builtin_amdgcn_readfirstlane(batch[a]);
        if (g != cur_g) {            // wave-uniform branch
            flush(cur_g);
            cur_g = g;
            load_grid(cur_g);
        }

        // wave-uniform scalar loads (constant-cache path)
        const float ax = atom_coord[a * 3 + 0];
        const float ay = atom_coord[a * 3 + 1];
        const float az = atom_coord[a * 3 + 2];
        const unsigned int* __restrict__ T = lds + (a - lo) * TSTRIDEP;

        // Batched: 4 r2 -> 4 sqrt -> 4 single-dword gathers -> 4 fma
        float fr[KPER]; int ii[KPER];
        #pragma unroll
        for (int j = 0; j < KPER; ++j) {
            const float dx = kx[j] - ax, dy = ky[j] - ay, dz = kz[j] - az;
            const float r2 = fmaf(dx, dx, fmaf(dy, dy, dz * dz));
            float tt = __builtin_amdgcn_sqrtf(r2) * ((float)NSEG / RMAX);
            tt = fminf(tt, (float)(NSEG - 1));
            const int i = (int)tt;            // tt >= 0: trunc == floor
            fr[j] = tt - (float)i;
            ii[j] = i;
        }
        unsigned int uu[KPER];
        #pragma unroll
        for (int j = 0; j < KPER; ++j) uu[j] = T[ii[j]];
        #pragma unroll
        for (int j = 0; j < KPER; ++j) {
            __half2 h2;
            __builtin_memcpy(&h2, &uu[j], 4);
            acc[j] = acc[j] + fmaf(fr[j], __high2float(h2), __low2float(h2));
        }
    }

    flush(cur_g);
}

extern "C" void kernel_launch(void* const* d_in, const int* in_sizes, int n_in,
                              void* d_out, int out_size, void* d_ws, size_t ws_size,
                              hipStream_t stream)
{
    const float* coeff      = (const float*)d_in[0];
    const float* atom_coord = (const float*)d_in[1];
    const float* grid       = (const float*)d_in[2];
    const int*   batch      = (const int*)d_in[3];
    float* out = (float*)d_out;
    unsigned int* table = (unsigned int*)d_ws;   // 3072 * 520 * 4B = 6.39 MB
    const int n_atoms = in_sizes[0] / N_GAUSS;

    GaussParams p;
    const double sqrt2pi = 2.50662827463100050242;
    for (int g = 0; g < N_GAUSS; ++g) {
        const double sigma = 0.5 + (5.0 - 0.5) * (double)g / (double)(N_GAUSS - 1);
        p.ns2[g] = (float)(-1.44269504088896340736 / (sigma * sigma));
        const double sr = 1.0 / (sigma * sqrt2pi * sigma * sqrt2pi * sigma * sqrt2pi);
        p.b[g] = (float)(std::log2(sr));
    }

    // 1) build packed tables + fused zero of out
    {
        dim3 gDim(2, n_atoms);
        hipLaunchKernelGGL(build_table_kernel, gDim, dim3(256), 0, stream,
                           coeff, table, out, p);
    }
    // 2) main gather/interp kernel
    {
        const int n_ablk = (n_atoms + APB - 1) / APB;   // 256
        dim3 gDim(CHUNKS, n_ablk);
        hipLaunchKernelGGL(GaussianOrbital_kernel, gDim, dim3(KCHUNK), 0, stream,
                           table, atom_coord, grid, batch, out, n_atoms);
    }
}